// Round 4
// baseline (647.725 us; speedup 1.0000x reference)
//
#include <hip/hip_runtime.h>
#include <hip/hip_bf16.h>
#include <cmath>

#define H_DIM 3584
#define NH 28
#define NKV 4
#define HD 128
#define S_LEN 2048
#define KQ 3584
#define KV_DIM 512
#define LDSK 72   // padded k-stride for fallback gemm

typedef __attribute__((ext_vector_type(8))) short bf16x8;
typedef __attribute__((ext_vector_type(4))) float f32x4;

__device__ __forceinline__ unsigned short f2bf(float f) {
  unsigned int u = __builtin_bit_cast(unsigned int, f);
  u += 0x7fffu + ((u >> 16) & 1u);
  return (unsigned short)(u >> 16);
}
__device__ __forceinline__ float bf2f(unsigned short h) {
  unsigned int u = ((unsigned int)h) << 16;
  return __builtin_bit_cast(float, u);
}

// ---------------- elementwise: fp32 -> bf16 ----------------
__global__ void cvt_f32_bf16(const float* __restrict__ in,
                             unsigned short* __restrict__ out, int n4) {
  int i = blockIdx.x * blockDim.x + threadIdx.x;
  if (i >= n4) return;
  float4 f = ((const float4*)in)[i];
  ushort4 v = make_ushort4(f2bf(f.x), f2bf(f.y), f2bf(f.z), f2bf(f.w));
  ((ushort4*)out)[i] = v;
}

// ---------------- RoPE on Q and K (in-place, bf16) ----------------
// Q additionally scaled by (1/sqrt(128))*log2(e) so attention works in the
// log2 domain with no per-score multiply.
__global__ void rope_kernel(unsigned short* __restrict__ Q,
                            unsigned short* __restrict__ Kr,
                            const int* __restrict__ pos_ids) {
  int gid = blockIdx.x * blockDim.x + threadIdx.x; // 2048 * 2048
  int s = gid >> 11;
  int p = gid & 2047;
  float pos = (float)pos_ids[s];
  unsigned short* ptr;
  int i;
  float fac;
  if (p < 1792) {           // Q: 28 heads * 64 pairs
    int head = p >> 6; i = p & 63;
    ptr = Q + (size_t)s * H_DIM + head * HD + i;
    fac = 0.12751743085547673f;   // (1/sqrt(128)) * log2(e)
  } else {                  // K: 4 heads * 64 pairs
    int pk = p - 1792; int head = pk >> 6; i = pk & 63;
    ptr = Kr + (size_t)s * KV_DIM + head * HD + i;
    fac = 1.0f;
  }
  float invf = exp2f(-(float)i * (19.931568569324174f / 64.0f)); // theta^(-i/64)
  float fr = pos * invf;
  float sn, cs;
  sincosf(fr, &sn, &cs);
  float x0 = bf2f(ptr[0]), x1 = bf2f(ptr[64]);
  ptr[0]  = f2bf((x0 * cs - x1 * sn) * fac);
  ptr[64] = f2bf((x1 * cs + x0 * sn) * fac);
}

// =======================================================================
// FAST GEMM: 128x128 tile, BK=64, global_load_lds width 16,
// explicit 2-phase LDS double-buffer.
// =======================================================================
__device__ __forceinline__ void gemm_core_db(const unsigned short* __restrict__ A,
                                             const unsigned short* __restrict__ B,
                                             int bm0, f32x4 (&acc)[4][4],
                                             unsigned short* As0, unsigned short* Bs0,
                                             unsigned short* As1, unsigned short* Bs1) {
  const int tid = threadIdx.x, lane = tid & 63, w = tid >> 6;
  const int wr = w >> 1, wc = w & 1, lr = lane & 15, lg = lane >> 4;
  const f32x4 zero4 = {0.f, 0.f, 0.f, 0.f};
#pragma unroll
  for (int m = 0; m < 4; ++m)
#pragma unroll
    for (int n = 0; n < 4; ++n) acc[m][n] = zero4;

  const int lrow = lane >> 3;        // 0..7
  const int lcol = (lane & 7) * 8;   // elem col within 64

  auto stage = [&](unsigned short* as, unsigned short* bs, int k0) {
#pragma unroll
    for (int j = 0; j < 4; ++j) {
      int id = w * 4 + j;            // 0..15, wave-uniform
      int row = id * 8 + lrow;       // 0..127
      __builtin_amdgcn_global_load_lds(
          (const __attribute__((address_space(1))) unsigned int*)(A + (size_t)(bm0 + row) * KQ + k0 + lcol),
          (__attribute__((address_space(3))) unsigned int*)(as + id * 512),
          16, 0, 0);
      __builtin_amdgcn_global_load_lds(
          (const __attribute__((address_space(1))) unsigned int*)(B + (size_t)row * KQ + k0 + lcol),
          (__attribute__((address_space(3))) unsigned int*)(bs + id * 512),
          16, 0, 0);
    }
  };
  auto compute = [&](const unsigned short* as, const unsigned short* bs) {
#pragma unroll
    for (int kh = 0; kh < 2; ++kh) {
      bf16x8 af[4], bfr[4];
#pragma unroll
      for (int m = 0; m < 4; ++m)
        af[m] = *(const bf16x8*)&as[(wr * 64 + m * 16 + lr) * 64 + kh * 32 + lg * 8];
#pragma unroll
      for (int n = 0; n < 4; ++n)
        bfr[n] = *(const bf16x8*)&bs[(wc * 64 + n * 16 + lr) * 64 + kh * 32 + lg * 8];
#pragma unroll
      for (int m = 0; m < 4; ++m)
#pragma unroll
        for (int n = 0; n < 4; ++n)
          acc[m][n] = __builtin_amdgcn_mfma_f32_16x16x32_bf16(af[m], bfr[n], acc[m][n], 0, 0, 0);
    }
  };

  stage(As0, Bs0, 0);
  __syncthreads();
  for (int k0 = 0; k0 < KQ; k0 += 128) {
    stage(As1, Bs1, k0 + 64);
    compute(As0, Bs0);
    __syncthreads();
    if (k0 + 128 < KQ) stage(As0, Bs0, k0 + 128);
    compute(As1, Bs1);
    __syncthreads();
  }
}

__global__ __launch_bounds__(256) void gemm_qkv_fast(
    const unsigned short* __restrict__ Xb,
    const unsigned short* __restrict__ Wqb, const float* __restrict__ bq,
    const unsigned short* __restrict__ Wkb, const float* __restrict__ bk,
    const unsigned short* __restrict__ Wvb, const float* __restrict__ bv,
    unsigned short* __restrict__ Qraw, unsigned short* __restrict__ Kraw,
    unsigned short* __restrict__ Vt) {
  __shared__ unsigned short As0[8192], Bs0[8192], As1[8192], Bs1[8192];
  const int id = blockIdx.x;
  const int swz = (id & 7) * 72 + (id >> 3);
  const int bm0 = (swz & 15) * 128;
  const int cb = swz >> 4;  // 0..35
  const unsigned short* Brows; const float* bias; int seg, c0;
  if (cb < 28)      { seg = 0; c0 = cb * 128;        Brows = Wqb + (size_t)c0 * KQ; bias = bq + c0; }
  else if (cb < 32) { seg = 1; c0 = (cb - 28) * 128; Brows = Wkb + (size_t)c0 * KQ; bias = bk + c0; }
  else              { seg = 2; c0 = (cb - 32) * 128; Brows = Wvb + (size_t)c0 * KQ; bias = bv + c0; }
  f32x4 acc[4][4];
  gemm_core_db(Xb, Brows, bm0, acc, As0, Bs0, As1, Bs1);
  const int tid = threadIdx.x, lane = tid & 63, w = tid >> 6;
  const int wr = w >> 1, wc = w & 1, lr = lane & 15, lg = lane >> 4;
#pragma unroll
  for (int m = 0; m < 4; ++m) {
#pragma unroll
    for (int n = 0; n < 4; ++n) {
      int coll = wc * 64 + n * 16 + lr;
      float bb = bias[coll];
      if (seg == 2) {
        int row = bm0 + wr * 64 + m * 16 + lg * 4;
        ushort4 o;
        o.x = f2bf(acc[m][n][0] + bb); o.y = f2bf(acc[m][n][1] + bb);
        o.z = f2bf(acc[m][n][2] + bb); o.w = f2bf(acc[m][n][3] + bb);
        *(ushort4*)&Vt[(size_t)(c0 + coll) * S_LEN + row] = o;
      } else {
#pragma unroll
        for (int r = 0; r < 4; ++r) {
          int row = bm0 + wr * 64 + m * 16 + lg * 4 + r;
          float v = acc[m][n][r] + bb;
          if (seg == 0) Qraw[(size_t)row * H_DIM + c0 + coll] = f2bf(v);
          else          Kraw[(size_t)row * KV_DIM + c0 + coll] = f2bf(v);
        }
      }
    }
  }
}

__global__ __launch_bounds__(256) void gemm_out_fast(
    const unsigned short* __restrict__ Ctx,
    const unsigned short* __restrict__ Wob,
    float* __restrict__ out) {
  __shared__ unsigned short As0[8192], Bs0[8192], As1[8192], Bs1[8192];
  const int id = blockIdx.x;
  const int swz = (id & 7) * 56 + (id >> 3);
  const int bm0 = (swz & 15) * 128;
  const int c0 = (swz >> 4) * 128;
  f32x4 acc[4][4];
  gemm_core_db(Ctx, Wob + (size_t)c0 * KQ, bm0, acc, As0, Bs0, As1, Bs1);
  const int tid = threadIdx.x, lane = tid & 63, w = tid >> 6;
  const int wr = w >> 1, wc = w & 1, lr = lane & 15, lg = lane >> 4;
#pragma unroll
  for (int m = 0; m < 4; ++m)
#pragma unroll
    for (int n = 0; n < 4; ++n) {
      int coll = wc * 64 + n * 16 + lr;
#pragma unroll
      for (int r = 0; r < 4; ++r) {
        int row = bm0 + wr * 64 + m * 16 + lg * 4 + r;
        out[(size_t)row * H_DIM + c0 + coll] = acc[m][n][r];
      }
    }
}

// =======================================================================
// FALLBACK GEMM (inline fp32->bf16 B conversion) — used if ws too small
// =======================================================================
__device__ __forceinline__ void gemm_core_slow(const unsigned short* __restrict__ A,
                                               const float* __restrict__ Brows,
                                               int bm0, f32x4 (&acc)[4][4],
                                               unsigned short* As, unsigned short* Bs) {
  const int tid = threadIdx.x;
  const int lane = tid & 63;
  const int w = tid >> 6;
  const int wr = w >> 1, wc = w & 1;
  const int lr = lane & 15, lg = lane >> 4;
  const f32x4 zero4 = {0.f, 0.f, 0.f, 0.f};
#pragma unroll
  for (int m = 0; m < 4; ++m)
#pragma unroll
    for (int n = 0; n < 4; ++n) acc[m][n] = zero4;

  for (int k0 = 0; k0 < KQ; k0 += 64) {
#pragma unroll
    for (int it = 0; it < 4; ++it) {
      int idx = tid + it * 256;
      int row = idx >> 3;
      int kc = (idx & 7) * 8;
      *(bf16x8*)&As[row * LDSK + kc] =
          *(const bf16x8*)&A[(size_t)(bm0 + row) * KQ + k0 + kc];
    }
#pragma unroll
    for (int it = 0; it < 4; ++it) {
      int idx = tid + it * 256;
      int row = idx >> 3;
      int kc = (idx & 7) * 8;
      const float* src = Brows + (size_t)row * KQ + k0 + kc;
      float4 f0 = *(const float4*)src;
      float4 f1 = *(const float4*)(src + 4);
      bf16x8 b;
      b[0] = (short)f2bf(f0.x); b[1] = (short)f2bf(f0.y);
      b[2] = (short)f2bf(f0.z); b[3] = (short)f2bf(f0.w);
      b[4] = (short)f2bf(f1.x); b[5] = (short)f2bf(f1.y);
      b[6] = (short)f2bf(f1.z); b[7] = (short)f2bf(f1.w);
      *(bf16x8*)&Bs[row * LDSK + kc] = b;
    }
    __syncthreads();
#pragma unroll
    for (int kh = 0; kh < 2; ++kh) {
      bf16x8 af[4], bfr[4];
#pragma unroll
      for (int m = 0; m < 4; ++m)
        af[m] = *(const bf16x8*)&As[(wr * 64 + m * 16 + lr) * LDSK + kh * 32 + lg * 8];
#pragma unroll
      for (int n = 0; n < 4; ++n)
        bfr[n] = *(const bf16x8*)&Bs[(wc * 64 + n * 16 + lr) * LDSK + kh * 32 + lg * 8];
#pragma unroll
      for (int m = 0; m < 4; ++m)
#pragma unroll
        for (int n = 0; n < 4; ++n)
          acc[m][n] = __builtin_amdgcn_mfma_f32_16x16x32_bf16(af[m], bfr[n], acc[m][n], 0, 0, 0);
    }
    __syncthreads();
  }
}

__global__ __launch_bounds__(256) void gemm_qkv_slow(
    const unsigned short* __restrict__ Xb,
    const float* __restrict__ wq, const float* __restrict__ bq,
    const float* __restrict__ wk, const float* __restrict__ bk,
    const float* __restrict__ wv, const float* __restrict__ bv,
    unsigned short* __restrict__ Qraw, unsigned short* __restrict__ Kraw,
    unsigned short* __restrict__ Vt) {
  __shared__ unsigned short As[128 * LDSK];
  __shared__ unsigned short Bs[128 * LDSK];
  const int bm0 = blockIdx.x * 128;
  const int cb = blockIdx.y;
  const float* Brows; const float* bias; int seg, c0;
  if (cb < 28)      { seg = 0; c0 = cb * 128;        Brows = wq + (size_t)c0 * KQ; bias = bq + c0; }
  else if (cb < 32) { seg = 1; c0 = (cb - 28) * 128; Brows = wk + (size_t)c0 * KQ; bias = bk + c0; }
  else              { seg = 2; c0 = (cb - 32) * 128; Brows = wv + (size_t)c0 * KQ; bias = bv + c0; }
  f32x4 acc[4][4];
  gemm_core_slow(Xb, Brows, bm0, acc, As, Bs);
  const int tid = threadIdx.x, lane = tid & 63, w = tid >> 6;
  const int wr = w >> 1, wc = w & 1, lr = lane & 15, lg = lane >> 4;
#pragma unroll
  for (int m = 0; m < 4; ++m) {
#pragma unroll
    for (int n = 0; n < 4; ++n) {
      int coll = wc * 64 + n * 16 + lr;
      float bb = bias[coll];
#pragma unroll
      for (int r = 0; r < 4; ++r) {
        int row = bm0 + wr * 64 + m * 16 + lg * 4 + r;
        float v = acc[m][n][r] + bb;
        if (seg == 0)      Qraw[(size_t)row * H_DIM + c0 + coll] = f2bf(v);
        else if (seg == 1) Kraw[(size_t)row * KV_DIM + c0 + coll] = f2bf(v);
        else               Vt[(size_t)(c0 + coll) * S_LEN + row] = f2bf(v);
      }
    }
  }
}

__global__ __launch_bounds__(256) void gemm_out_slow(
    const unsigned short* __restrict__ Ctx,
    const float* __restrict__ wo,
    float* __restrict__ out) {
  __shared__ unsigned short As[128 * LDSK];
  __shared__ unsigned short Bs[128 * LDSK];
  const int bm0 = blockIdx.x * 128;
  const int c0 = blockIdx.y * 128;
  f32x4 acc[4][4];
  gemm_core_slow(Ctx, wo + (size_t)c0 * KQ, bm0, acc, As, Bs);
  const int tid = threadIdx.x, lane = tid & 63, w = tid >> 6;
  const int wr = w >> 1, wc = w & 1, lr = lane & 15, lg = lane >> 4;
#pragma unroll
  for (int m = 0; m < 4; ++m)
#pragma unroll
    for (int n = 0; n < 4; ++n) {
      int coll = wc * 64 + n * 16 + lr;
#pragma unroll
      for (int r = 0; r < 4; ++r) {
        int row = bm0 + wr * 64 + m * 16 + lg * 4 + r;
        out[(size_t)row * H_DIM + c0 + coll] = acc[m][n][r];
      }
    }
}

// =======================================================================
// Flash attention v4: swapped-operand QK^T (lane owns ONE query -> scalar
// softmax, 2 shuffle rounds), PV as O^T = mfma(V^T, P^T) with in-register
// P redistribution (8 dword shfl + 4 selects, no LDS). 4 independent waves
// per block (same head, adjacent q-tiles), K reg double-buffer, defer-max.
// Q pre-scaled by (1/sqrt(D))*log2e in rope -> log2-domain softmax.
// =======================================================================
__global__ __launch_bounds__(256, 3) void attn4_kernel(
    const unsigned short* __restrict__ Q,
    const unsigned short* __restrict__ K,
    const unsigned short* __restrict__ Vt,
    unsigned short* __restrict__ Ctx) {
  const int bid = blockIdx.x;
  const int xcd = bid & 7;
  const int kvg = xcd >> 1;                     // 2 XCDs per kv-group
  const int mm = ((bid >> 3) << 1) | (xcd & 1); // 0..223
  const int hsub = mm % 7;
  const int qtb = 31 - mm / 7;                  // heavy q-blocks first
  const int h = kvg * 7 + hsub;
  const int hkv = kvg;
  const int w = threadIdx.x >> 6;
  const int lane = threadIdx.x & 63;
  const int lr = lane & 15, lg = lane >> 4;
  const int q0 = (qtb * 4 + w) * 16;
  const int myq = q0 + lr;                      // this lane's query row

  const f32x4 zero4 = {0.f, 0.f, 0.f, 0.f};

  // Q fragment (B-operand: col=query=lr, k-chunk d = ds*32 + lg*8)
  bf16x8 aq[4];
  const unsigned short* qrow = Q + (size_t)myq * H_DIM + h * HD;
#pragma unroll
  for (int ds = 0; ds < 4; ++ds) aq[ds] = *(const bf16x8*)(qrow + ds * 32 + lg * 8);

  f32x4 acc[8];
#pragma unroll
  for (int t = 0; t < 8; ++t) acc[t] = zero4;
  float mrun = -1e30f, lrun = 0.f;

  const unsigned short* kbase = K + hkv * HD + (size_t)lr * KV_DIM + lg * 8;
  const unsigned short* vbase = Vt + (size_t)(hkv * HD + lr) * S_LEN + lg * 8;

  const int nkt = (q0 + 47) >> 5;   // 32-key tiles, causal

  bf16x8 kra[2][4], krb[2][4];

  auto loadk = [&](bf16x8 (&dst)[2][4], int kt) {
    const int kk0 = kt * 32;
#pragma unroll
    for (int kf = 0; kf < 2; ++kf)
#pragma unroll
      for (int ds = 0; ds < 4; ++ds)
        dst[kf][ds] = *(const bf16x8*)(kbase + (size_t)(kk0 + kf * 16) * KV_DIM + ds * 32);
  };

  auto process = [&](int kt, bf16x8 (&cur)[2][4], bf16x8 (&nxt)[2][4]) {
    const int kk0 = kt * 32;
    if (kt + 1 < nkt) loadk(nxt, kt + 1);   // prefetch next K tile
    bf16x8 vreg[4];                          // first half of V early
#pragma unroll
    for (int t = 0; t < 4; ++t)
      vreg[t] = *(const bf16x8*)(vbase + (size_t)(t * 16) * S_LEN + kk0);
    // S^T = K · Q : D[key][query], col=lane&15=query, row=lg*4+r=key
    f32x4 s[2];
    s[0] = zero4; s[1] = zero4;
    __builtin_amdgcn_s_setprio(1);
#pragma unroll
    for (int ds = 0; ds < 4; ++ds) {
      s[0] = __builtin_amdgcn_mfma_f32_16x16x32_bf16(cur[0][ds], aq[ds], s[0], 0, 0, 0);
      s[1] = __builtin_amdgcn_mfma_f32_16x16x32_bf16(cur[1][ds], aq[ds], s[1], 0, 0, 0);
    }
    __builtin_amdgcn_s_setprio(0);
    // causal mask (scores already in log2 domain via pre-scaled Q)
    float sv[2][4];
#pragma unroll
    for (int kf = 0; kf < 2; ++kf)
#pragma unroll
      for (int r = 0; r < 4; ++r) {
        int key = kk0 + kf * 16 + lg * 4 + r;
        sv[kf][r] = (key > myq) ? -1e30f : s[kf][r];
      }
    // row max: 7 in-lane fmax + 2 shuffle rounds (lanes sharing lr)
    float mt = fmaxf(fmaxf(fmaxf(sv[0][0], sv[0][1]), fmaxf(sv[0][2], sv[0][3])),
                     fmaxf(fmaxf(sv[1][0], sv[1][1]), fmaxf(sv[1][2], sv[1][3])));
    mt = fmaxf(mt, __shfl_xor(mt, 16));
    mt = fmaxf(mt, __shfl_xor(mt, 32));
    // defer-max: rescale only when max grew past threshold (log2 units)
    if (__any(mt > mrun + 8.0f)) {
      float mnew = fmaxf(mrun, mt);
      float alpha = exp2f(mrun - mnew);
      mrun = mnew;
      lrun *= alpha;
#pragma unroll
      for (int t = 0; t < 8; ++t)
#pragma unroll
        for (int r = 0; r < 4; ++r) acc[t][r] *= alpha;
    }
    // p = exp2(sv - m); scalar row-sum: 7 adds + 2 shuffles
    float p[2][4];
    float lt = 0.f;
#pragma unroll
    for (int kf = 0; kf < 2; ++kf)
#pragma unroll
      for (int r = 0; r < 4; ++r) {
        p[kf][r] = exp2f(sv[kf][r] - mrun);
        lt += p[kf][r];
      }
    lt += __shfl_xor(lt, 16);
    lt += __shfl_xor(lt, 32);
    lrun += lt;
    // pack P -> bf16 dwords; redistribute to B-operand layout via shfl
    unsigned int pk00 = ((unsigned int)f2bf(p[0][1]) << 16) | f2bf(p[0][0]);
    unsigned int pk01 = ((unsigned int)f2bf(p[0][3]) << 16) | f2bf(p[0][2]);
    unsigned int pk10 = ((unsigned int)f2bf(p[1][1]) << 16) | f2bf(p[1][0]);
    unsigned int pk11 = ((unsigned int)f2bf(p[1][3]) << 16) | f2bf(p[1][2]);
    const int sA = lr + ((lg & 1) << 5);
    const int sB = sA + 16;
    const bool hi = (lg >> 1) != 0;
    unsigned int a0 = __shfl((int)pk00, sA), b0 = __shfl((int)pk10, sA);
    unsigned int a1 = __shfl((int)pk01, sA), b1 = __shfl((int)pk11, sA);
    unsigned int a2 = __shfl((int)pk00, sB), b2 = __shfl((int)pk10, sB);
    unsigned int a3 = __shfl((int)pk01, sB), b3 = __shfl((int)pk11, sB);
    uint4 udw = make_uint4(hi ? b0 : a0, hi ? b1 : a1, hi ? b2 : a2, hi ? b3 : a3);
    bf16x8 pb = __builtin_bit_cast(bf16x8, udw);
    // PV: O^T = V^T · P^T  (A=Vt rows: row=d=lr, k=keys lg*8..+8; B=pb)
    __builtin_amdgcn_s_setprio(1);
#pragma unroll
    for (int t = 0; t < 4; ++t)
      acc[t] = __builtin_amdgcn_mfma_f32_16x16x32_bf16(vreg[t], pb, acc[t], 0, 0, 0);
    __builtin_amdgcn_s_setprio(0);
    bf16x8 vreg2[4];
#pragma unroll
    for (int t = 0; t < 4; ++t)
      vreg2[t] = *(const bf16x8*)(vbase + (size_t)((t + 4) * 16) * S_LEN + kk0);
    __builtin_amdgcn_s_setprio(1);
#pragma unroll
    for (int t = 0; t < 4; ++t)
      acc[t + 4] = __builtin_amdgcn_mfma_f32_16x16x32_bf16(vreg2[t], pb, acc[t + 4], 0, 0, 0);
    __builtin_amdgcn_s_setprio(0);
  };

  loadk(kra, 0);
  for (int kt = 0; kt < nkt; kt += 2) {
    process(kt, kra, krb);
    if (kt + 1 < nkt) process(kt + 1, krb, kra);
  }

  // O[q][d]: acc[t][r] = O[myq][t*16 + lg*4 + r] -> packed 8B stores
  float inv = 1.0f / lrun;
  unsigned short* orow = Ctx + (size_t)myq * H_DIM + h * HD + lg * 4;
#pragma unroll
  for (int t = 0; t < 8; ++t) {
    ushort4 o;
    o.x = f2bf(acc[t][0] * inv);
    o.y = f2bf(acc[t][1] * inv);
    o.z = f2bf(acc[t][2] * inv);
    o.w = f2bf(acc[t][3] * inv);
    *(ushort4*)(orow + t * 16) = o;
  }
}

extern "C" void kernel_launch(void* const* d_in, const int* in_sizes, int n_in,
                              void* d_out, int out_size, void* d_ws, size_t ws_size,
                              hipStream_t stream) {
  (void)in_sizes; (void)n_in; (void)out_size;
  const float* hidden = (const float*)d_in[0];
  const float* wq = (const float*)d_in[1];
  const float* bq = (const float*)d_in[2];
  const float* wk = (const float*)d_in[3];
  const float* bk = (const float*)d_in[4];
  const float* wv = (const float*)d_in[5];
  const float* bv = (const float*)d_in[6];
  const float* wo = (const float*)d_in[7];
  const int* pos = (const int*)d_in[8];
  float* out = (float*)d_out;

  const size_t N_X   = (size_t)S_LEN * H_DIM;   // 7,340,032
  const size_t N_KV  = (size_t)S_LEN * KV_DIM;  // 1,048,576
  const size_t N_WQ  = (size_t)NH * HD * H_DIM; // 12,845,056
  const size_t N_WK  = (size_t)NKV * HD * H_DIM;// 1,835,008

  unsigned short* Xb   = (unsigned short*)d_ws;
  unsigned short* Qraw = Xb   + N_X;
  unsigned short* Kraw = Qraw + N_X;
  unsigned short* Vt   = Kraw + N_KV;
  unsigned short* Ctx  = Vt   + N_KV;
  unsigned short* Wqb  = Ctx  + N_X;
  unsigned short* Wkb  = Wqb  + N_WQ;
  unsigned short* Wvb  = Wkb  + N_WK;
  unsigned short* Wob  = Wvb  + N_WK;

  const size_t NEED_FAST = (3 * N_X + 2 * N_KV + 2 * N_WQ + 2 * N_WK) * sizeof(unsigned short);
  const bool fast = ws_size >= NEED_FAST;

  cvt_f32_bf16<<<(int)(N_X / 4 / 256), 256, 0, stream>>>(hidden, Xb, (int)(N_X / 4));

  if (fast) {
    cvt_f32_bf16<<<(int)(N_WQ / 4 / 256), 256, 0, stream>>>(wq, Wqb, (int)(N_WQ / 4));
    cvt_f32_bf16<<<(int)(N_WK / 4 / 256), 256, 0, stream>>>(wk, Wkb, (int)(N_WK / 4));
    cvt_f32_bf16<<<(int)(N_WK / 4 / 256), 256, 0, stream>>>(wv, Wvb, (int)(N_WK / 4));
    cvt_f32_bf16<<<(int)(N_WQ / 4 / 256), 256, 0, stream>>>(wo, Wob, (int)(N_WQ / 4));
    gemm_qkv_fast<<<576, 256, 0, stream>>>(Xb, Wqb, bq, Wkb, bk, Wvb, bv, Qraw, Kraw, Vt);
  } else {
    gemm_qkv_slow<<<dim3(16, 36), 256, 0, stream>>>(Xb, wq, bq, wk, bk, wv, bv, Qraw, Kraw, Vt);
  }

  rope_kernel<<<(S_LEN * 2048) / 256, 256, 0, stream>>>(Qraw, Kraw, pos);
  attn4_kernel<<<NH * 32, 256, 0, stream>>>(Qraw, Kraw, Vt, Ctx);

  if (fast) {
    gemm_out_fast<<<448, 256, 0, stream>>>(Ctx, Wob, out);
  } else {
    gemm_out_slow<<<dim3(16, 28), 256, 0, stream>>>(Ctx, wo, out);
  }
}

// Round 5
// 620.810 us; speedup vs baseline: 1.0434x; 1.0434x over previous
//
#include <hip/hip_runtime.h>
#include <hip/hip_bf16.h>
#include <cmath>

#define H_DIM 3584
#define NH 28
#define NKV 4
#define HD 128
#define S_LEN 2048
#define KQ 3584
#define KV_DIM 512
#define LDSK 72      // padded k-stride for fallback gemm
#define PSTRIDE 4608 // fp32 partial row stride (Q 3584 | K 512 | V 512)

typedef __attribute__((ext_vector_type(8))) short bf16x8;
typedef __attribute__((ext_vector_type(4))) float f32x4;

__device__ __forceinline__ unsigned short f2bf(float f) {
  unsigned int u = __builtin_bit_cast(unsigned int, f);
  u += 0x7fffu + ((u >> 16) & 1u);
  return (unsigned short)(u >> 16);
}
__device__ __forceinline__ float bf2f(unsigned short h) {
  unsigned int u = ((unsigned int)h) << 16;
  return __builtin_bit_cast(float, u);
}

// ---------------- elementwise: fp32 -> bf16 ----------------
__global__ void cvt_f32_bf16(const float* __restrict__ in,
                             unsigned short* __restrict__ out, int n4) {
  int i = blockIdx.x * blockDim.x + threadIdx.x;
  if (i >= n4) return;
  float4 f = ((const float4*)in)[i];
  ushort4 v = make_ushort4(f2bf(f.x), f2bf(f.y), f2bf(f.z), f2bf(f.w));
  ((ushort4*)out)[i] = v;
}

// all four weight matrices in one launch
__global__ void cvt_weights(const float* __restrict__ wq, const float* __restrict__ wk,
                            const float* __restrict__ wv, const float* __restrict__ wo,
                            unsigned short* __restrict__ Wqb, unsigned short* __restrict__ Wkb,
                            unsigned short* __restrict__ Wvb, unsigned short* __restrict__ Wob) {
  const int NQ4 = (NH * HD * H_DIM) / 4;   // 3,211,264
  const int NK4 = (NKV * HD * H_DIM) / 4;  // 458,752
  int i = blockIdx.x * blockDim.x + threadIdx.x;
  const float* src; unsigned short* dst; int off;
  if (i < NQ4)                { src = wq; dst = Wqb; off = i; }
  else if (i < NQ4 + NK4)     { src = wk; dst = Wkb; off = i - NQ4; }
  else if (i < NQ4 + 2 * NK4) { src = wv; dst = Wvb; off = i - NQ4 - NK4; }
  else                        { src = wo; dst = Wob; off = i - NQ4 - 2 * NK4; }
  float4 f = ((const float4*)src)[off];
  ushort4 v = make_ushort4(f2bf(f.x), f2bf(f.y), f2bf(f.z), f2bf(f.w));
  ((ushort4*)dst)[off] = v;
}

// ---------------- RoPE on Q and K (in-place, bf16) ----------------
// Q additionally scaled by (1/sqrt(128))*log2(e) -> log2-domain attention.
__global__ void rope_kernel(unsigned short* __restrict__ Q,
                            unsigned short* __restrict__ Kr,
                            const int* __restrict__ pos_ids) {
  int gid = blockIdx.x * blockDim.x + threadIdx.x; // 2048 * 2048
  int s = gid >> 11;
  int p = gid & 2047;
  float pos = (float)pos_ids[s];
  unsigned short* ptr;
  int i;
  float fac;
  if (p < 1792) {           // Q: 28 heads * 64 pairs
    int head = p >> 6; i = p & 63;
    ptr = Q + (size_t)s * H_DIM + head * HD + i;
    fac = 0.12751743085547673f;   // (1/sqrt(128)) * log2(e)
  } else {                  // K: 4 heads * 64 pairs
    int pk = p - 1792; int head = pk >> 6; i = pk & 63;
    ptr = Kr + (size_t)s * KV_DIM + head * HD + i;
    fac = 1.0f;
  }
  float invf = exp2f(-(float)i * (19.931568569324174f / 64.0f)); // theta^(-i/64)
  float fr = pos * invf;
  float sn, cs;
  sincosf(fr, &sn, &cs);
  float x0 = bf2f(ptr[0]), x1 = bf2f(ptr[64]);
  ptr[0]  = f2bf((x0 * cs - x1 * sn) * fac);
  ptr[64] = f2bf((x1 * cs + x0 * sn) * fac);
}

// =======================================================================
// GEMM core: 128x128 tile, BK=64, global_load_lds width 16, explicit
// 2-phase LDS double-buffer; K range [k_lo, k_lo+k_len) (k_len % 128 == 0).
// =======================================================================
__device__ __forceinline__ void gemm_core_db(const unsigned short* __restrict__ A,
                                             const unsigned short* __restrict__ B,
                                             int bm0, int k_lo, int k_len,
                                             f32x4 (&acc)[4][4],
                                             unsigned short* As0, unsigned short* Bs0,
                                             unsigned short* As1, unsigned short* Bs1) {
  const int tid = threadIdx.x, lane = tid & 63, w = tid >> 6;
  const int wr = w >> 1, wc = w & 1, lr = lane & 15, lg = lane >> 4;
  const f32x4 zero4 = {0.f, 0.f, 0.f, 0.f};
#pragma unroll
  for (int m = 0; m < 4; ++m)
#pragma unroll
    for (int n = 0; n < 4; ++n) acc[m][n] = zero4;

  const int lrow = lane >> 3;        // 0..7
  const int lcol = (lane & 7) * 8;   // elem col within 64

  auto stage = [&](unsigned short* as, unsigned short* bs, int k0) {
#pragma unroll
    for (int j = 0; j < 4; ++j) {
      int id = w * 4 + j;            // 0..15, wave-uniform
      int row = id * 8 + lrow;       // 0..127
      __builtin_amdgcn_global_load_lds(
          (const __attribute__((address_space(1))) unsigned int*)(A + (size_t)(bm0 + row) * KQ + k0 + lcol),
          (__attribute__((address_space(3))) unsigned int*)(as + id * 512),
          16, 0, 0);
      __builtin_amdgcn_global_load_lds(
          (const __attribute__((address_space(1))) unsigned int*)(B + (size_t)row * KQ + k0 + lcol),
          (__attribute__((address_space(3))) unsigned int*)(bs + id * 512),
          16, 0, 0);
    }
  };
  auto compute = [&](const unsigned short* as, const unsigned short* bs) {
#pragma unroll
    for (int kh = 0; kh < 2; ++kh) {
      bf16x8 af[4], bfr[4];
#pragma unroll
      for (int m = 0; m < 4; ++m)
        af[m] = *(const bf16x8*)&as[(wr * 64 + m * 16 + lr) * 64 + kh * 32 + lg * 8];
#pragma unroll
      for (int n = 0; n < 4; ++n)
        bfr[n] = *(const bf16x8*)&bs[(wc * 64 + n * 16 + lr) * 64 + kh * 32 + lg * 8];
#pragma unroll
      for (int m = 0; m < 4; ++m)
#pragma unroll
        for (int n = 0; n < 4; ++n)
          acc[m][n] = __builtin_amdgcn_mfma_f32_16x16x32_bf16(af[m], bfr[n], acc[m][n], 0, 0, 0);
    }
  };

  const int k_end = k_lo + k_len;
  stage(As0, Bs0, k_lo);
  __syncthreads();
  for (int k0 = k_lo; k0 < k_end; k0 += 128) {
    stage(As1, Bs1, k0 + 64);
    compute(As0, Bs0);
    __syncthreads();
    if (k0 + 128 < k_end) stage(As0, Bs0, k0 + 128);
    compute(As1, Bs1);
    __syncthreads();
  }
}

// ---------------- split-K QKV: fp32 partials ----------------
__global__ __launch_bounds__(256) void gemm_qkv_sk(
    const unsigned short* __restrict__ Xb,
    const unsigned short* __restrict__ Wqb,
    const unsigned short* __restrict__ Wkb,
    const unsigned short* __restrict__ Wvb,
    float* __restrict__ Ppart) {
  __shared__ unsigned short As0[8192], Bs0[8192], As1[8192], Bs1[8192];
  const int id = blockIdx.x;
  const int swz = (id & 7) * 72 + (id >> 3);
  const int bm0 = (swz & 15) * 128;
  const int cb = swz >> 4;  // 0..35
  const unsigned short* Brows; int c0abs;
  if (cb < 28)      { Brows = Wqb + (size_t)cb * 128 * KQ;        c0abs = cb * 128; }
  else if (cb < 32) { Brows = Wkb + (size_t)(cb - 28) * 128 * KQ; c0abs = 3584 + (cb - 28) * 128; }
  else              { Brows = Wvb + (size_t)(cb - 32) * 128 * KQ; c0abs = 4096 + (cb - 32) * 128; }
  float* P = Ppart + (size_t)blockIdx.y * ((size_t)S_LEN * PSTRIDE);
  f32x4 acc[4][4];
  gemm_core_db(Xb, Brows, bm0, blockIdx.y * 1792, 1792, acc, As0, Bs0, As1, Bs1);
  const int tid = threadIdx.x, lane = tid & 63, w = tid >> 6;
  const int wr = w >> 1, wc = w & 1, lr = lane & 15, lg = lane >> 4;
#pragma unroll
  for (int m = 0; m < 4; ++m)
#pragma unroll
    for (int n = 0; n < 4; ++n) {
      int coll = wc * 64 + n * 16 + lr;
#pragma unroll
      for (int r = 0; r < 4; ++r) {
        int row = bm0 + wr * 64 + m * 16 + lg * 4 + r;
        P[(size_t)row * PSTRIDE + c0abs + coll] = acc[m][n][r];
      }
    }
}

// ---------------- combine QKV partials: +bias, ->bf16, V transposed -------
__global__ void combine_qkv(const float* __restrict__ P0, const float* __restrict__ P1,
                            const float* __restrict__ bq, const float* __restrict__ bk,
                            const float* __restrict__ bv,
                            unsigned short* __restrict__ Qraw,
                            unsigned short* __restrict__ Kraw,
                            unsigned short* __restrict__ Vt) {
  int id = blockIdx.x * 256 + threadIdx.x;
  if (id < 2048 * 1024) {               // Q+K: 2048 rows x 4096 cols, 4/thread
    int row = id >> 10;
    int col = (id & 1023) << 2;
    float4 p0 = *(const float4*)&P0[(size_t)row * PSTRIDE + col];
    float4 p1 = *(const float4*)&P1[(size_t)row * PSTRIDE + col];
    if (col < H_DIM) {
      float4 bb = *(const float4*)&bq[col];
      ushort4 o;
      o.x = f2bf(p0.x + p1.x + bb.x); o.y = f2bf(p0.y + p1.y + bb.y);
      o.z = f2bf(p0.z + p1.z + bb.z); o.w = f2bf(p0.w + p1.w + bb.w);
      *(ushort4*)&Qraw[(size_t)row * H_DIM + col] = o;
    } else {
      int kc = col - H_DIM;
      float4 bb = *(const float4*)&bk[kc];
      ushort4 o;
      o.x = f2bf(p0.x + p1.x + bb.x); o.y = f2bf(p0.y + p1.y + bb.y);
      o.z = f2bf(p0.z + p1.z + bb.z); o.w = f2bf(p0.w + p1.w + bb.w);
      *(ushort4*)&Kraw[(size_t)row * KV_DIM + kc] = o;
    }
  } else {                              // V: transpose, 512 cols x 512 rowgroups
    int vid = id - 2048 * 1024;
    int rg = vid >> 9;
    int vcol = vid & 511;
    int row0 = rg << 2;
    float bb = bv[vcol];
    ushort4 o;
    o.x = f2bf(P0[(size_t)(row0 + 0) * PSTRIDE + 4096 + vcol] + P1[(size_t)(row0 + 0) * PSTRIDE + 4096 + vcol] + bb);
    o.y = f2bf(P0[(size_t)(row0 + 1) * PSTRIDE + 4096 + vcol] + P1[(size_t)(row0 + 1) * PSTRIDE + 4096 + vcol] + bb);
    o.z = f2bf(P0[(size_t)(row0 + 2) * PSTRIDE + 4096 + vcol] + P1[(size_t)(row0 + 2) * PSTRIDE + 4096 + vcol] + bb);
    o.w = f2bf(P0[(size_t)(row0 + 3) * PSTRIDE + 4096 + vcol] + P1[(size_t)(row0 + 3) * PSTRIDE + 4096 + vcol] + bb);
    *(ushort4*)&Vt[(size_t)vcol * S_LEN + row0] = o;
  }
}

// ---------------- split-K out-proj ----------------
__global__ __launch_bounds__(256) void gemm_out_sk(
    const unsigned short* __restrict__ Ctx,
    const unsigned short* __restrict__ Wob,
    float* __restrict__ Ppart) {
  __shared__ unsigned short As0[8192], Bs0[8192], As1[8192], Bs1[8192];
  const int id = blockIdx.x;
  const int swz = (id & 7) * 56 + (id >> 3);
  const int bm0 = (swz & 15) * 128;
  const int c0 = (swz >> 4) * 128;
  float* P = Ppart + (size_t)blockIdx.y * ((size_t)S_LEN * PSTRIDE);
  f32x4 acc[4][4];
  gemm_core_db(Ctx, Wob + (size_t)c0 * KQ, bm0, blockIdx.y * 1792, 1792, acc, As0, Bs0, As1, Bs1);
  const int tid = threadIdx.x, lane = tid & 63, w = tid >> 6;
  const int wr = w >> 1, wc = w & 1, lr = lane & 15, lg = lane >> 4;
#pragma unroll
  for (int m = 0; m < 4; ++m)
#pragma unroll
    for (int n = 0; n < 4; ++n) {
      int coll = wc * 64 + n * 16 + lr;
#pragma unroll
      for (int r = 0; r < 4; ++r) {
        int row = bm0 + wr * 64 + m * 16 + lg * 4 + r;
        P[(size_t)row * PSTRIDE + c0 + coll] = acc[m][n][r];
      }
    }
}

__global__ void combine_out(const float* __restrict__ P0, const float* __restrict__ P1,
                            float* __restrict__ out) {
  int id = blockIdx.x * 256 + threadIdx.x;  // 2048 * 896
  int row = id / 896;
  int col = (id % 896) * 4;
  float4 a = *(const float4*)&P0[(size_t)row * PSTRIDE + col];
  float4 b = *(const float4*)&P1[(size_t)row * PSTRIDE + col];
  float4 o = make_float4(a.x + b.x, a.y + b.y, a.z + b.z, a.w + b.w);
  *(float4*)&out[(size_t)row * H_DIM + col] = o;
}

// ---------------- non-split fast GEMMs (fallback tier) ----------------
__global__ __launch_bounds__(256) void gemm_qkv_fast(
    const unsigned short* __restrict__ Xb,
    const unsigned short* __restrict__ Wqb, const float* __restrict__ bq,
    const unsigned short* __restrict__ Wkb, const float* __restrict__ bk,
    const unsigned short* __restrict__ Wvb, const float* __restrict__ bv,
    unsigned short* __restrict__ Qraw, unsigned short* __restrict__ Kraw,
    unsigned short* __restrict__ Vt) {
  __shared__ unsigned short As0[8192], Bs0[8192], As1[8192], Bs1[8192];
  const int id = blockIdx.x;
  const int swz = (id & 7) * 72 + (id >> 3);
  const int bm0 = (swz & 15) * 128;
  const int cb = swz >> 4;
  const unsigned short* Brows; const float* bias; int seg, c0;
  if (cb < 28)      { seg = 0; c0 = cb * 128;        Brows = Wqb + (size_t)c0 * KQ; bias = bq + c0; }
  else if (cb < 32) { seg = 1; c0 = (cb - 28) * 128; Brows = Wkb + (size_t)c0 * KQ; bias = bk + c0; }
  else              { seg = 2; c0 = (cb - 32) * 128; Brows = Wvb + (size_t)c0 * KQ; bias = bv + c0; }
  f32x4 acc[4][4];
  gemm_core_db(Xb, Brows, bm0, 0, KQ, acc, As0, Bs0, As1, Bs1);
  const int tid = threadIdx.x, lane = tid & 63, w = tid >> 6;
  const int wr = w >> 1, wc = w & 1, lr = lane & 15, lg = lane >> 4;
#pragma unroll
  for (int m = 0; m < 4; ++m) {
#pragma unroll
    for (int n = 0; n < 4; ++n) {
      int coll = wc * 64 + n * 16 + lr;
      float bb = bias[coll];
      if (seg == 2) {
        int row = bm0 + wr * 64 + m * 16 + lg * 4;
        ushort4 o;
        o.x = f2bf(acc[m][n][0] + bb); o.y = f2bf(acc[m][n][1] + bb);
        o.z = f2bf(acc[m][n][2] + bb); o.w = f2bf(acc[m][n][3] + bb);
        *(ushort4*)&Vt[(size_t)(c0 + coll) * S_LEN + row] = o;
      } else {
#pragma unroll
        for (int r = 0; r < 4; ++r) {
          int row = bm0 + wr * 64 + m * 16 + lg * 4 + r;
          float v = acc[m][n][r] + bb;
          if (seg == 0) Qraw[(size_t)row * H_DIM + c0 + coll] = f2bf(v);
          else          Kraw[(size_t)row * KV_DIM + c0 + coll] = f2bf(v);
        }
      }
    }
  }
}

__global__ __launch_bounds__(256) void gemm_out_fast(
    const unsigned short* __restrict__ Ctx,
    const unsigned short* __restrict__ Wob,
    float* __restrict__ out) {
  __shared__ unsigned short As0[8192], Bs0[8192], As1[8192], Bs1[8192];
  const int id = blockIdx.x;
  const int swz = (id & 7) * 56 + (id >> 3);
  const int bm0 = (swz & 15) * 128;
  const int c0 = (swz >> 4) * 128;
  f32x4 acc[4][4];
  gemm_core_db(Ctx, Wob + (size_t)c0 * KQ, bm0, 0, KQ, acc, As0, Bs0, As1, Bs1);
  const int tid = threadIdx.x, lane = tid & 63, w = tid >> 6;
  const int wr = w >> 1, wc = w & 1, lr = lane & 15, lg = lane >> 4;
#pragma unroll
  for (int m = 0; m < 4; ++m)
#pragma unroll
    for (int n = 0; n < 4; ++n) {
      int coll = wc * 64 + n * 16 + lr;
#pragma unroll
      for (int r = 0; r < 4; ++r) {
        int row = bm0 + wr * 64 + m * 16 + lg * 4 + r;
        out[(size_t)row * H_DIM + c0 + coll] = acc[m][n][r];
      }
    }
}

// ---------------- slow GEMMs (tiny-ws fallback) ----------------
__device__ __forceinline__ void gemm_core_slow(const unsigned short* __restrict__ A,
                                               const float* __restrict__ Brows,
                                               int bm0, f32x4 (&acc)[4][4],
                                               unsigned short* As, unsigned short* Bs) {
  const int tid = threadIdx.x;
  const int lane = tid & 63;
  const int w = tid >> 6;
  const int wr = w >> 1, wc = w & 1;
  const int lr = lane & 15, lg = lane >> 4;
  const f32x4 zero4 = {0.f, 0.f, 0.f, 0.f};
#pragma unroll
  for (int m = 0; m < 4; ++m)
#pragma unroll
    for (int n = 0; n < 4; ++n) acc[m][n] = zero4;

  for (int k0 = 0; k0 < KQ; k0 += 64) {
#pragma unroll
    for (int it = 0; it < 4; ++it) {
      int idx = tid + it * 256;
      int row = idx >> 3;
      int kc = (idx & 7) * 8;
      *(bf16x8*)&As[row * LDSK + kc] =
          *(const bf16x8*)&A[(size_t)(bm0 + row) * KQ + k0 + kc];
    }
#pragma unroll
    for (int it = 0; it < 4; ++it) {
      int idx = tid + it * 256;
      int row = idx >> 3;
      int kc = (idx & 7) * 8;
      const float* src = Brows + (size_t)row * KQ + k0 + kc;
      float4 f0 = *(const float4*)src;
      float4 f1 = *(const float4*)(src + 4);
      bf16x8 b;
      b[0] = (short)f2bf(f0.x); b[1] = (short)f2bf(f0.y);
      b[2] = (short)f2bf(f0.z); b[3] = (short)f2bf(f0.w);
      b[4] = (short)f2bf(f1.x); b[5] = (short)f2bf(f1.y);
      b[6] = (short)f2bf(f1.z); b[7] = (short)f2bf(f1.w);
      *(bf16x8*)&Bs[row * LDSK + kc] = b;
    }
    __syncthreads();
#pragma unroll
    for (int kh = 0; kh < 2; ++kh) {
      bf16x8 af[4], bfr[4];
#pragma unroll
      for (int m = 0; m < 4; ++m)
        af[m] = *(const bf16x8*)&As[(wr * 64 + m * 16 + lr) * LDSK + kh * 32 + lg * 8];
#pragma unroll
      for (int n = 0; n < 4; ++n)
        bfr[n] = *(const bf16x8*)&Bs[(wc * 64 + n * 16 + lr) * LDSK + kh * 32 + lg * 8];
#pragma unroll
      for (int m = 0; m < 4; ++m)
#pragma unroll
        for (int n = 0; n < 4; ++n)
          acc[m][n] = __builtin_amdgcn_mfma_f32_16x16x32_bf16(af[m], bfr[n], acc[m][n], 0, 0, 0);
    }
    __syncthreads();
  }
}

__global__ __launch_bounds__(256) void gemm_qkv_slow(
    const unsigned short* __restrict__ Xb,
    const float* __restrict__ wq, const float* __restrict__ bq,
    const float* __restrict__ wk, const float* __restrict__ bk,
    const float* __restrict__ wv, const float* __restrict__ bv,
    unsigned short* __restrict__ Qraw, unsigned short* __restrict__ Kraw,
    unsigned short* __restrict__ Vt) {
  __shared__ unsigned short As[128 * LDSK];
  __shared__ unsigned short Bs[128 * LDSK];
  const int bm0 = blockIdx.x * 128;
  const int cb = blockIdx.y;
  const float* Brows; const float* bias; int seg, c0;
  if (cb < 28)      { seg = 0; c0 = cb * 128;        Brows = wq + (size_t)c0 * KQ; bias = bq + c0; }
  else if (cb < 32) { seg = 1; c0 = (cb - 28) * 128; Brows = wk + (size_t)c0 * KQ; bias = bk + c0; }
  else              { seg = 2; c0 = (cb - 32) * 128; Brows = wv + (size_t)c0 * KQ; bias = bv + c0; }
  f32x4 acc[4][4];
  gemm_core_slow(Xb, Brows, bm0, acc, As, Bs);
  const int tid = threadIdx.x, lane = tid & 63, w = tid >> 6;
  const int wr = w >> 1, wc = w & 1, lr = lane & 15, lg = lane >> 4;
#pragma unroll
  for (int m = 0; m < 4; ++m) {
#pragma unroll
    for (int n = 0; n < 4; ++n) {
      int coll = wc * 64 + n * 16 + lr;
      float bb = bias[coll];
#pragma unroll
      for (int r = 0; r < 4; ++r) {
        int row = bm0 + wr * 64 + m * 16 + lg * 4 + r;
        float v = acc[m][n][r] + bb;
        if (seg == 0)      Qraw[(size_t)row * H_DIM + c0 + coll] = f2bf(v);
        else if (seg == 1) Kraw[(size_t)row * KV_DIM + c0 + coll] = f2bf(v);
        else               Vt[(size_t)(c0 + coll) * S_LEN + row] = f2bf(v);
      }
    }
  }
}

__global__ __launch_bounds__(256) void gemm_out_slow(
    const unsigned short* __restrict__ Ctx,
    const float* __restrict__ wo,
    float* __restrict__ out) {
  __shared__ unsigned short As[128 * LDSK];
  __shared__ unsigned short Bs[128 * LDSK];
  const int bm0 = blockIdx.x * 128;
  const int c0 = blockIdx.y * 128;
  f32x4 acc[4][4];
  gemm_core_slow(Ctx, wo + (size_t)c0 * KQ, bm0, acc, As, Bs);
  const int tid = threadIdx.x, lane = tid & 63, w = tid >> 6;
  const int wr = w >> 1, wc = w & 1, lr = lane & 15, lg = lane >> 4;
#pragma unroll
  for (int m = 0; m < 4; ++m)
#pragma unroll
    for (int n = 0; n < 4; ++n) {
      int coll = wc * 64 + n * 16 + lr;
#pragma unroll
      for (int r = 0; r < 4; ++r) {
        int row = bm0 + wr * 64 + m * 16 + lg * 4 + r;
        out[(size_t)row * H_DIM + c0 + coll] = acc[m][n][r];
      }
    }
}

// =======================================================================
// Flash attention v5 (attn3 structure, log2 domain, optional KV-split):
// 1 wave/block, 16 q-rows, 32-key tiles, K reg double-buffer, early V
// issue, per-wave LDS P transpose, setprio, heavy-first XCD swizzle.
// SPLIT=1: blockIdx.y selects half of the key range; writes unnormalized
// fp32 O + (m,l) partials, merged by attn_merge.
// =======================================================================
template <int SPLIT>
__global__ __launch_bounds__(64) void attn5_kernel(
    const unsigned short* __restrict__ Q,
    const unsigned short* __restrict__ K,
    const unsigned short* __restrict__ Vt,
    unsigned short* __restrict__ Ctx,
    float* __restrict__ Opart, float2* __restrict__ MLpart) {
  __shared__ unsigned short plds[16][40];
  const int bid = blockIdx.x;
  const int xcd = bid & 7;
  const int kvg = xcd >> 1;
  const int mm = ((bid >> 3) << 1) | (xcd & 1);  // 0..895
  const int hsub = mm % 7;
  const int qt = 127 - mm / 7;
  const int h = kvg * 7 + hsub;
  const int hkv = kvg;
  const int lane = threadIdx.x & 63;
  const int lr = lane & 15, lg = lane >> 4;
  const int q0 = qt * 16;
  const f32x4 zero4 = {0.f, 0.f, 0.f, 0.f};

  bf16x8 aq[4];
  const unsigned short* qrow = Q + (size_t)(q0 + lr) * H_DIM + h * HD;
#pragma unroll
  for (int ds = 0; ds < 4; ++ds) aq[ds] = *(const bf16x8*)(qrow + ds * 32 + lg * 8);

  f32x4 acc[8];
#pragma unroll
  for (int t = 0; t < 8; ++t) acc[t] = zero4;
  float mrun[4] = {-1e30f, -1e30f, -1e30f, -1e30f};
  float lrun[4] = {0.f, 0.f, 0.f, 0.f};

  const unsigned short* kbase = K + hkv * HD + (size_t)lr * KV_DIM + lg * 8;
  const unsigned short* vbase = Vt + (size_t)(hkv * HD + lr) * S_LEN + lg * 8;

  const int nkt = (q0 + 47) >> 5;   // 32-key tiles, causal
  int t_lo = 0, t_hi = nkt;
  if (SPLIT) {
    int hh = (nkt + 1) >> 1;
    if (blockIdx.y == 0) t_hi = hh; else t_lo = hh;
  }

  bf16x8 kra[2][4], krb[2][4];

  auto loadk = [&](bf16x8 (&dst)[2][4], int kt) {
    const int kk0 = kt * 32;
#pragma unroll
    for (int kf = 0; kf < 2; ++kf)
#pragma unroll
      for (int ds = 0; ds < 4; ++ds)
        dst[kf][ds] = *(const bf16x8*)(kbase + (size_t)(kk0 + kf * 16) * KV_DIM + ds * 32);
  };

  auto process = [&](int kt, bf16x8 (&cur)[2][4], bf16x8 (&nxt)[2][4]) {
    const int kk0 = kt * 32;
    if (kt + 1 < t_hi) loadk(nxt, kt + 1);   // prefetch next K tile
    bf16x8 vreg[8];                          // early V issue
#pragma unroll
    for (int t = 0; t < 8; ++t)
      vreg[t] = *(const bf16x8*)(vbase + (size_t)(t * 16) * S_LEN + kk0);
    f32x4 s[2];
    s[0] = zero4; s[1] = zero4;
    __builtin_amdgcn_s_setprio(1);
#pragma unroll
    for (int ds = 0; ds < 4; ++ds) {
      s[0] = __builtin_amdgcn_mfma_f32_16x16x32_bf16(aq[ds], cur[0][ds], s[0], 0, 0, 0);
      s[1] = __builtin_amdgcn_mfma_f32_16x16x32_bf16(aq[ds], cur[1][ds], s[1], 0, 0, 0);
    }
    __builtin_amdgcn_s_setprio(0);
    // scores already log2-scaled (Q pre-scaled in rope)
    float sv[2][4];
#pragma unroll
    for (int kf = 0; kf < 2; ++kf) {
      int key = kk0 + kf * 16 + lr;
#pragma unroll
      for (int r = 0; r < 4; ++r) {
        int qr = q0 + lg * 4 + r;
        sv[kf][r] = (key > qr) ? -1e30f : s[kf][r];
      }
    }
    float mt[4];
#pragma unroll
    for (int r = 0; r < 4; ++r) mt[r] = fmaxf(sv[0][r], sv[1][r]);
#pragma unroll
    for (int sh = 0; sh < 4; ++sh) {
      int off = 1 << sh;
#pragma unroll
      for (int r = 0; r < 4; ++r) mt[r] = fmaxf(mt[r], __shfl_xor(mt[r], off));
    }
    bool need = false;
#pragma unroll
    for (int r = 0; r < 4; ++r) need = need || (mt[r] > mrun[r]);
    if (__any(need)) {
#pragma unroll
      for (int r = 0; r < 4; ++r) {
        float mnew = fmaxf(mrun[r], mt[r]);
        float alpha = exp2f(mrun[r] - mnew);
        mrun[r] = mnew;
        lrun[r] *= alpha;
#pragma unroll
        for (int t = 0; t < 8; ++t) acc[t][r] *= alpha;
      }
    }
    float lt[4] = {0.f, 0.f, 0.f, 0.f};
#pragma unroll
    for (int kf = 0; kf < 2; ++kf)
#pragma unroll
      for (int r = 0; r < 4; ++r) {
        float p = exp2f(sv[kf][r] - mrun[r]);
        lt[r] += p;
        plds[lg * 4 + r][kf * 16 + lr] = f2bf(p);
      }
#pragma unroll
    for (int sh = 0; sh < 4; ++sh) {
      int off = 1 << sh;
#pragma unroll
      for (int r = 0; r < 4; ++r) lt[r] += __shfl_xor(lt[r], off);
    }
#pragma unroll
    for (int r = 0; r < 4; ++r) lrun[r] += lt[r];
    bf16x8 pa = *(const bf16x8*)&plds[lr][lg * 8];
    __builtin_amdgcn_s_setprio(1);
#pragma unroll
    for (int t = 0; t < 8; ++t)
      acc[t] = __builtin_amdgcn_mfma_f32_16x16x32_bf16(pa, vreg[t], acc[t], 0, 0, 0);
    __builtin_amdgcn_s_setprio(0);
  };

  if (t_lo < t_hi) {
    loadk(kra, t_lo);
    for (int kt = t_lo; kt < t_hi; kt += 2) {
      process(kt, kra, krb);
      if (kt + 1 < t_hi) process(kt + 1, krb, kra);
    }
  }

  if (SPLIT) {
    float* Od = Opart + (size_t)blockIdx.y * ((size_t)NH * S_LEN * HD);
    float2* MLd = MLpart + (size_t)blockIdx.y * ((size_t)NH * S_LEN);
#pragma unroll
    for (int r = 0; r < 4; ++r) {
      int q = q0 + lg * 4 + r;
#pragma unroll
      for (int t = 0; t < 8; ++t)
        Od[((size_t)h * S_LEN + q) * HD + t * 16 + lr] = acc[t][r];
    }
    if (lr == 0) {
#pragma unroll
      for (int r = 0; r < 4; ++r)
        MLd[(size_t)h * S_LEN + q0 + lg * 4 + r] = make_float2(mrun[r], lrun[r]);
    }
  } else {
#pragma unroll
    for (int r = 0; r < 4; ++r) {
      float inv = 1.0f / lrun[r];
#pragma unroll
      for (int t = 0; t < 8; ++t)
        Ctx[(size_t)(q0 + lg * 4 + r) * H_DIM + h * HD + t * 16 + lr] = f2bf(acc[t][r] * inv);
    }
  }
}

__global__ void attn_merge(const float* __restrict__ O0, const float* __restrict__ O1,
                           const float2* __restrict__ ML0, const float2* __restrict__ ML1,
                           unsigned short* __restrict__ Ctx) {
  int id = blockIdx.x * 256 + threadIdx.x;   // 28*2048*32
  int hq = id >> 5;
  int d = (id & 31) << 2;
  int h = hq >> 11;
  int q = hq & 2047;
  float2 a = ML0[hq], b = ML1[hq];
  float M = fmaxf(a.x, b.x);
  float w0 = exp2f(a.x - M), w1 = exp2f(b.x - M);
  float inv = 1.0f / (w0 * a.y + w1 * b.y);
  float4 o0 = *(const float4*)&O0[(size_t)hq * HD + d];
  float4 o1 = *(const float4*)&O1[(size_t)hq * HD + d];
  ushort4 o;
  o.x = f2bf((o0.x * w0 + o1.x * w1) * inv);
  o.y = f2bf((o0.y * w0 + o1.y * w1) * inv);
  o.z = f2bf((o0.z * w0 + o1.z * w1) * inv);
  o.w = f2bf((o0.w * w0 + o1.w * w1) * inv);
  *(ushort4*)&Ctx[(size_t)q * H_DIM + h * HD + d] = o;
}

extern "C" void kernel_launch(void* const* d_in, const int* in_sizes, int n_in,
                              void* d_out, int out_size, void* d_ws, size_t ws_size,
                              hipStream_t stream) {
  (void)in_sizes; (void)n_in; (void)out_size;
  const float* hidden = (const float*)d_in[0];
  const float* wq = (const float*)d_in[1];
  const float* bq = (const float*)d_in[2];
  const float* wk = (const float*)d_in[3];
  const float* bk = (const float*)d_in[4];
  const float* wv = (const float*)d_in[5];
  const float* bv = (const float*)d_in[6];
  const float* wo = (const float*)d_in[7];
  const int* pos = (const int*)d_in[8];
  float* out = (float*)d_out;

  const size_t N_X  = (size_t)S_LEN * H_DIM;    // 7,340,032
  const size_t N_KV = (size_t)S_LEN * KV_DIM;   // 1,048,576
  const size_t N_WQ = (size_t)NH * HD * H_DIM;  // 12,845,056
  const size_t N_WK = (size_t)NKV * HD * H_DIM; // 1,835,008
  const size_t N_P  = (size_t)S_LEN * PSTRIDE;  // 9,437,184 fp32 per split
  const size_t N_O  = (size_t)NH * S_LEN * HD;  // 7,340,032 fp32 per split

  unsigned short* Xb   = (unsigned short*)d_ws;
  unsigned short* Qraw = Xb   + N_X;
  unsigned short* Kraw = Qraw + N_X;
  unsigned short* Vt   = Kraw + N_KV;
  unsigned short* Ctx  = Vt   + N_KV;
  unsigned short* Wqb  = Ctx  + N_X;
  unsigned short* Wkb  = Wqb  + N_WQ;
  unsigned short* Wvb  = Wkb  + N_WK;
  unsigned short* Wob  = Wvb  + N_WK;
  float* scratch = (float*)(Wob + N_WQ);        // shared partial region
  float* P0 = scratch;
  float* P1 = scratch + N_P;
  float* O0 = scratch;                          // reused after GEMM combine
  float* O1 = scratch + N_O;
  float2* ML0 = (float2*)(scratch + 2 * N_O);
  float2* ML1 = ML0 + (size_t)NH * S_LEN;

  const size_t NEED_FAST  = (3 * N_X + 2 * N_KV + 2 * N_WQ + 2 * N_WK) * sizeof(unsigned short);
  const size_t NEED_SPLIT = NEED_FAST + 2 * N_P * sizeof(float);
  const bool fast  = ws_size >= NEED_FAST;
  const bool split = ws_size >= NEED_SPLIT;

  cvt_f32_bf16<<<(int)(N_X / 4 / 256), 256, 0, stream>>>(hidden, Xb, (int)(N_X / 4));

  if (fast) {
    cvt_weights<<<(int)((2 * N_WQ + 2 * N_WK) / 4 / 256), 256, 0, stream>>>(
        wq, wk, wv, wo, Wqb, Wkb, Wvb, Wob);
    if (split) {
      gemm_qkv_sk<<<dim3(576, 2), 256, 0, stream>>>(Xb, Wqb, Wkb, Wvb, P0);
      combine_qkv<<<9216, 256, 0, stream>>>(P0, P1, bq, bk, bv, Qraw, Kraw, Vt);
    } else {
      gemm_qkv_fast<<<576, 256, 0, stream>>>(Xb, Wqb, bq, Wkb, bk, Wvb, bv, Qraw, Kraw, Vt);
    }
  } else {
    gemm_qkv_slow<<<dim3(16, 36), 256, 0, stream>>>(Xb, wq, bq, wk, bk, wv, bv, Qraw, Kraw, Vt);
  }

  rope_kernel<<<(S_LEN * 2048) / 256, 256, 0, stream>>>(Qraw, Kraw, pos);

  if (split) {
    attn5_kernel<1><<<dim3(3584, 2), 64, 0, stream>>>(Qraw, Kraw, Vt, Ctx, O0, ML0);
    attn_merge<<<7168, 256, 0, stream>>>(O0, O1, ML0, ML1, Ctx);
  } else {
    attn5_kernel<0><<<dim3(3584, 1), 64, 0, stream>>>(Qraw, Kraw, Vt, Ctx, nullptr, nullptr);
  }

  if (fast) {
    if (split) {
      gemm_out_sk<<<dim3(448, 2), 256, 0, stream>>>(Ctx, Wob, P0);
      combine_out<<<7168, 256, 0, stream>>>(P0, P1, out);
    } else {
      gemm_out_fast<<<448, 256, 0, stream>>>(Ctx, Wob, out);
    }
  } else {
    gemm_out_slow<<<dim3(16, 28), 256, 0, stream>>>(Ctx, wo, out);
  }
}